// Round 3
// baseline (4492.345 us; speedup 1.0000x reference)
//
#include <hip/hip_runtime.h>

typedef __attribute__((ext_vector_type(8))) short short8;
typedef __attribute__((ext_vector_type(4))) float f32x4;

#define N_ATOMS_C 100000
#define N_EDGES_C 200000
#define ATOM_DIM_C 133
#define BOND_DIM_C 14
#define HID_C 512

#define KT0 5   // ceil(147/32)
#define KT1 16  // 512/32
#define KT2 21  // ceil(645/32)

template <int N> struct IC { static constexpr int v = N; };

__device__ __forceinline__ unsigned short bf16_rne(float f) {
  unsigned int u = __float_as_uint(f);
  unsigned int r = (u + 0x7fffu + ((u >> 16) & 1u)) >> 16;
  return (unsigned short)r;
}
__device__ __forceinline__ float bf16_to_f(unsigned short h) {
  return __uint_as_float(((unsigned int)h) << 16);
}

// Pre-split weight W [512][K] into bf16 hi/lo planes in MFMA B-fragment order:
// plane[nb][kt][frag*64+lane] = 8 bf16 of W[nb*256+frag*16+(lane&15)][kt*32+(lane>>4)*8+j]
template <int K, int KTILES>
__global__ __launch_bounds__(256) void prep_w(const float* __restrict__ W,
                                              short8* __restrict__ hi,
                                              short8* __restrict__ lo) {
  const int idx = blockIdx.x * 256 + threadIdx.x;
  if (idx >= 2 * KTILES * 1024) return;
  const int nb = idx / (KTILES * 1024);
  const int rem = idx - nb * (KTILES * 1024);
  const int kt = rem >> 10;
  const int c = rem & 1023;
  const int l = c & 63;
  const int n = nb * 256 + ((c >> 6) << 4) + (l & 15);
  const int k0 = kt * 32 + ((l >> 4) << 3);
  short8 h8, l8;
#pragma unroll
  for (int j = 0; j < 8; ++j) {
    const int k = k0 + j;
    const float f = (k < K) ? W[(size_t)n * K + k] : 0.f;
    const unsigned short hb = bf16_rne(f);
    h8[j] = (short)hb;
    l8[j] = (short)bf16_rne(f - bf16_to_f(hb));
  }
  hi[idx] = h8;
  lo[idx] = l8;
}

// MODE 0: h0 = relu([V[src[e]];E[e]] @ W_i^T)              in0=V,  in1=E
// MODE 1: h' = relu((m2a[src]-w[e^1]h[e^1]) @ W_h^T + h0)  in0=m2a,in1=h_prev
// MODE 2: ha = relu([V;m_final] @ W_o^T + b_o)             in0=V,  in1=m_final
// SCATTER: epilogue fuses m2a_next[dst[e]] += (wscat?wscat[e]:1) * out
template <int MODE, int KTILES, bool SCATTER>
__global__ __launch_bounds__(256, 2) void mfma_gemm(
    const short8* __restrict__ wHi, const short8* __restrict__ wLo,
    const float* __restrict__ in0, const float* __restrict__ in1,
    const float* __restrict__ addv, const float* __restrict__ wrev,
    const int* __restrict__ srcp, const int* __restrict__ dstp,
    const float* __restrict__ wscat, float* __restrict__ C,
    float* __restrict__ m2a, int M) {
  __shared__ short8 Ah[2][256], Al[2][256];  // [dbuf][frag-linear 4x64]
  __shared__ int sSrc[64], sDst[64];
  __shared__ float sWe[64], sWrev[64];

  const int tid = threadIdx.x;
  // bijective XCD swizzle (m204); col-block pairs adjacent for L2 reuse
  const int nwg = gridDim.x;
  const int qq = nwg >> 3, rr = nwg & 7;
  const int x = blockIdx.x & 7, o = blockIdx.x >> 3;
  const int wg = (x < rr ? x * (qq + 1) : rr * (qq + 1) + (x - rr) * qq) + o;
  const int cb = wg & 1, rb = wg >> 1;
  const int bm0 = rb * 64, bn0 = cb * 256;

  if (tid < 64) {
    const int e = bm0 + tid;
    const int ec = e < M ? e : M - 1;
    if (MODE != 2) sSrc[tid] = srcp[ec];
    if (SCATTER) {
      sDst[tid] = dstp[ec];
      sWe[tid] = wscat ? wscat[ec] : 1.f;
    }
    if (MODE == 1) sWrev[tid] = wrev[ec ^ 1];
  }
  __syncthreads();

  const int w = tid >> 6, lane = tid & 63;
  const int r = tid >> 2, kc = tid & 3;  // staging: row r, k-chunk kc (8 wide)
  const int arow = bm0 + r;
  const int arc = arow < M ? arow : M - 1;
  const int aslot = ((r >> 4) << 6) | (kc << 4) | (r & 15);
  constexpr int KTOT = (MODE == 0) ? 147 : 645;

  const float* p0 = nullptr;
  const float* p1 = nullptr;
  float wr_ = 0.f;
  if (MODE == 0) {
    p0 = in0 + (size_t)sSrc[r] * ATOM_DIM_C;
    p1 = in1 + (size_t)arc * BOND_DIM_C;
  } else if (MODE == 1) {
    p0 = in0 + ((size_t)sSrc[r] << 9);
    p1 = in1 + ((size_t)(arc ^ 1) << 9);
    wr_ = sWrev[r];
  } else {
    p0 = in0 + (size_t)arc * ATOM_DIM_C;
    p1 = in1 + ((size_t)arc << 9);
  }

  const short8* gHi = wHi + (size_t)cb * KTILES * 1024;
  const short8* gLo = wLo + (size_t)cb * KTILES * 1024;
  const int boff = (w << 8) + lane;

  f32x4 acc[4][4];
#pragma unroll
  for (int i = 0; i < 4; ++i)
#pragma unroll
    for (int j = 0; j < 4; ++j) acc[i][j] = f32x4{0.f, 0.f, 0.f, 0.f};

  // ---- register prefetch state (all indices compile-time) ----
  float4 pa0[2], pa1[2], pg0[2], pg1[2];  // MODE1 A prefetch
  float vA[2][8];                         // MODE0/2 A prefetch
  short8 pbh[2][4], pbl[2][4];            // B fragment prefetch

  auto loadA = [&](auto sc, int t) {
    constexpr int S = decltype(sc)::v;
    const int k0 = t * 32 + kc * 8;
    if (MODE == 1) {
      pa0[S] = *(const float4*)(p0 + k0);
      pa1[S] = *(const float4*)(p0 + k0 + 4);
      pg0[S] = *(const float4*)(p1 + k0);
      pg1[S] = *(const float4*)(p1 + k0 + 4);
    } else {
#pragma unroll
      for (int j = 0; j < 8; ++j) {
        const int k = k0 + j;
        float f = 0.f;
        if (k < ATOM_DIM_C) f = p0[k];
        else if (k < KTOT) f = p1[k - ATOM_DIM_C];
        vA[S][j] = f;
      }
    }
  };
  auto loadB = [&](auto sc, int t) {
    constexpr int S = decltype(sc)::v;
    const short8* gh = gHi + ((size_t)t << 10) + boff;
    const short8* gl = gLo + ((size_t)t << 10) + boff;
#pragma unroll
    for (int nj = 0; nj < 4; ++nj) {
      pbh[S][nj] = gh[nj << 6];
      pbl[S][nj] = gl[nj << 6];
    }
  };
  auto splitW = [&](auto sc, int buf) {
    constexpr int S = decltype(sc)::v;
    float v[8];
    if (MODE == 1) {
      v[0] = pa0[S].x - wr_ * pg0[S].x;
      v[1] = pa0[S].y - wr_ * pg0[S].y;
      v[2] = pa0[S].z - wr_ * pg0[S].z;
      v[3] = pa0[S].w - wr_ * pg0[S].w;
      v[4] = pa1[S].x - wr_ * pg1[S].x;
      v[5] = pa1[S].y - wr_ * pg1[S].y;
      v[6] = pa1[S].z - wr_ * pg1[S].z;
      v[7] = pa1[S].w - wr_ * pg1[S].w;
    } else {
#pragma unroll
      for (int j = 0; j < 8; ++j) v[j] = vA[S][j];
    }
    short8 h8, l8;
#pragma unroll
    for (int j = 0; j < 8; ++j) {
      const unsigned short hb = bf16_rne(v[j]);
      h8[j] = (short)hb;
      l8[j] = (short)bf16_rne(v[j] - bf16_to_f(hb));
    }
    Ah[buf][aslot] = h8;
    Al[buf][aslot] = l8;
  };

  auto stepf = [&](auto cc, int t) {
    constexpr int CUR = decltype(cc)::v;
    // 1. A fragments from LDS (written at t-1)
    short8 ah[4], al[4];
#pragma unroll
    for (int mi = 0; mi < 4; ++mi) {
      ah[mi] = Ah[CUR][(mi << 6) + lane];
      al[mi] = Al[CUR][(mi << 6) + lane];
    }
    // 2. issue next-next A gather early (no deps; stays in flight across MFMA)
    if (t + 2 < KTILES) loadA(IC<CUR>{}, t + 2);
    // 3. split-bf16 triple MFMA (compiler waits lgkm for ah/al, vmcnt for B set)
#pragma unroll
    for (int mi = 0; mi < 4; ++mi)
#pragma unroll
      for (int nj = 0; nj < 4; ++nj) {
        acc[mi][nj] = __builtin_amdgcn_mfma_f32_16x16x32_bf16(ah[mi], pbh[CUR][nj], acc[mi][nj], 0, 0, 0);
        acc[mi][nj] = __builtin_amdgcn_mfma_f32_16x16x32_bf16(al[mi], pbh[CUR][nj], acc[mi][nj], 0, 0, 0);
        acc[mi][nj] = __builtin_amdgcn_mfma_f32_16x16x32_bf16(ah[mi], pbl[CUR][nj], acc[mi][nj], 0, 0, 0);
      }
    // 4. split A(t+1) (loaded at t-1; latency fully covered) -> other LDS buf
    if (t + 1 < KTILES) splitW(IC<CUR ^ 1>{}, CUR ^ 1);
    // 5. reload B set CUR with tile t+2 (WAR after MFMA use)
    if (t + 2 < KTILES) loadB(IC<CUR>{}, t + 2);
    // 6. single barrier per tile; loads remain in flight across it
    __syncthreads();
  };

  // ---- prologue ----
  loadA(IC<0>{}, 0);
  loadB(IC<0>{}, 0);
  splitW(IC<0>{}, 0);
  if (KTILES > 1) {
    loadA(IC<1>{}, 1);
    loadB(IC<1>{}, 1);
  }
  __syncthreads();

  // ---- main loop: one barrier per K-tile ----
  for (int t = 0; t < KTILES; t += 2) {
    stepf(IC<0>{}, t);
    if (t + 1 < KTILES) stepf(IC<1>{}, t + 1);
  }

  // ---- epilogue: +h0/+b_o, relu, store, fused weighted scatter-add ----
  const int lq = lane >> 4, lc = lane & 15;
#pragma unroll
  for (int mi = 0; mi < 4; ++mi) {
#pragma unroll
    for (int nj = 0; nj < 4; ++nj) {
      const int ccol = bn0 + (((w << 2) + nj) << 4) + lc;
      const f32x4 a = acc[mi][nj];
#pragma unroll
      for (int q2 = 0; q2 < 4; ++q2) {
        const int rloc = (mi << 4) + (lq << 2) + q2;
        const int row = bm0 + rloc;
        if (row < M) {
          float xv = a[q2];
          if (MODE == 1) xv += addv[((size_t)row << 9) + ccol];
          if (MODE == 2) xv += addv[ccol];
          xv = fmaxf(xv, 0.f);
          C[((size_t)row << 9) + ccol] = xv;
          if (SCATTER) atomicAdd(m2a + ((size_t)sDst[rloc] << 9) + ccol, sWe[rloc] * xv);
        }
      }
    }
  }
}

__global__ __launch_bounds__(256) void batch_copy_kernel(const int* __restrict__ b,
                                                         float* __restrict__ o) {
  const int i = blockIdx.x * 256 + threadIdx.x;
  if (i < N_ATOMS_C) o[i] = (float)b[i];
}

extern "C" void kernel_launch(void* const* d_in, const int* in_sizes, int n_in,
                              void* d_out, int out_size, void* d_ws, size_t ws_size,
                              hipStream_t stream) {
  const float* V = (const float*)d_in[0];
  const float* E = (const float*)d_in[1];
  const int* edge_index = (const int*)d_in[2];
  const int* batch = (const int*)d_in[4];
  const float* weight = (const float*)d_in[5];
  const float* W_i = (const float*)d_in[6];
  const float* W_h = (const float*)d_in[7];
  const float* W_o = (const float*)d_in[8];
  const float* b_o = (const float*)d_in[9];

  const int* src = edge_index;
  const int* dst = edge_index + N_EDGES_C;

  // ws: h0(400MB) | hA(400MB) | mA(200MB) | mB(200MB) | weight planes (~2.8MB)
  float* ws = (float*)d_ws;
  float* h0 = ws;
  float* hA = h0 + (size_t)N_EDGES_C * HID_C;
  float* mA = hA + (size_t)N_EDGES_C * HID_C;
  float* mB = mA + (size_t)N_ATOMS_C * HID_C;
  short8* wiHi = (short8*)(mB + (size_t)N_ATOMS_C * HID_C);
  short8* wiLo = wiHi + 2 * KT0 * 1024;
  short8* whHi = wiLo + 2 * KT0 * 1024;
  short8* whLo = whHi + 2 * KT1 * 1024;
  short8* woHi = whLo + 2 * KT1 * 1024;
  short8* woLo = woHi + 2 * KT2 * 1024;

  // out: h_atom [100000*512] | atom_batch [100000] | h [200000*512]
  float* out = (float*)d_out;
  float* out_hatom = out;
  float* out_batch = out + (size_t)N_ATOMS_C * HID_C;
  float* out_h = out_batch + N_ATOMS_C;

  prep_w<147, KT0><<<(2 * KT0 * 1024 + 255) / 256, 256, 0, stream>>>(W_i, wiHi, wiLo);
  prep_w<512, KT1><<<(2 * KT1 * 1024 + 255) / 256, 256, 0, stream>>>(W_h, whHi, whLo);
  prep_w<645, KT2><<<(2 * KT2 * 1024 + 255) / 256, 256, 0, stream>>>(W_o, woHi, woLo);

  const size_t mBytes = (size_t)N_ATOMS_C * HID_C * sizeof(float);
  const int gE = (N_EDGES_C / 64) * 2;         // 6250
  const int gA = ((N_ATOMS_C + 63) / 64) * 2;  // 3126

  // h0 = relu([V[src];E] Wi^T); mA += w*h0
  hipMemsetAsync(mA, 0, mBytes, stream);
  mfma_gemm<0, KT0, true><<<gE, 256, 0, stream>>>(wiHi, wiLo, V, E, nullptr, nullptr,
                                                  src, dst, weight, h0, mA, N_EDGES_C);
  // t=0: h1 = relu((mA[src]-w^rev h0^rev)Wh^T + h0) -> out_h; mB += w*h1
  hipMemsetAsync(mB, 0, mBytes, stream);
  mfma_gemm<1, KT1, true><<<gE, 256, 0, stream>>>(whHi, whLo, mA, h0, h0, weight,
                                                  src, dst, weight, out_h, mB, N_EDGES_C);
  // t=1: h2 -> hA; mA += w*h2
  hipMemsetAsync(mA, 0, mBytes, stream);
  mfma_gemm<1, KT1, true><<<gE, 256, 0, stream>>>(whHi, whLo, mB, out_h, h0, weight,
                                                  src, dst, weight, hA, mA, N_EDGES_C);
  // t=2: h3 -> out_h; mB += 1.0*h3  (= m_final)
  hipMemsetAsync(mB, 0, mBytes, stream);
  mfma_gemm<1, KT1, true><<<gE, 256, 0, stream>>>(whHi, whLo, mA, hA, h0, weight,
                                                  src, dst, nullptr, out_h, mB, N_EDGES_C);
  // h_atom = relu([V;m_final] Wo^T + b_o)
  mfma_gemm<2, KT2, false><<<gA, 256, 0, stream>>>(woHi, woLo, V, mB, b_o, nullptr,
                                                   nullptr, nullptr, nullptr, out_hatom,
                                                   nullptr, N_ATOMS_C);
  batch_copy_kernel<<<(N_ATOMS_C + 255) / 256, 256, 0, stream>>>(batch, out_batch);
}